// Round 2
// baseline (1504.963 us; speedup 1.0000x reference)
//
#include <hip/hip_runtime.h>
#include <hip/hip_bf16.h>

// EGNN encoder, N=50000 nodes, E=250000 edges, D=128, L=4.
// Runtime dtype-adaptive: detect bf16-vs-fp32 inputs from ln_g[0] (all-ones:
// first u16 is 0x3F80 iff bf16, 0x0000 iff fp32 little-endian).
//
// Algebra: h = silu(A[src]+B[tgt]+dist*w1c), A=x@W1a+eb1, B=x@W1b
//          agg = Hagg@EW2 + deg*eb2, Hagg = scatter_add(h, tgt)
//          msg.pw1 = h.(EW2@pw1) + eb2.pw1  (precomputed w2p/c2p per layer)

#define NNODES 50000
#define NEDGES 250000

typedef unsigned short u16;
typedef __attribute__((ext_vector_type(8))) short bf16x8;
typedef __attribute__((ext_vector_type(4))) float floatx4;

__device__ __forceinline__ float b2f(u16 h){ unsigned u=((unsigned)h)<<16; float f; __builtin_memcpy(&f,&u,4); return f; }
__device__ __forceinline__ u16 f2b(float f){ unsigned u; __builtin_memcpy(&u,&f,4); u = u + 0x7FFFu + ((u>>16)&1u); return (u16)(u>>16); }
__device__ __forceinline__ float siluf(float x){ return x/(1.f+__expf(-x)); }
// dtype-adaptive element load (element index i, not bytes)
__device__ __forceinline__ float ldf(const void* p, long i, int isbf){
  return isbf ? b2f(((const u16*)p)[i]) : ((const float*)p)[i];
}

__global__ void detect_kernel(const void* lng, int* flag){
  if (threadIdx.x==0 && blockIdx.x==0) *flag = (((const u16*)lng)[0] != 0) ? 1 : 0;
}

// ---------- weight packing into MFMA B-fragment order ----------
// packed[((kk*8+nt)*64+lane)*8+j] = W[kk*32+(lane>>4)*8+j][nt*16+(lane&15)]
__global__ __launch_bounds__(256) void pack_kernel(
    const void* __restrict__ ew1, const void* __restrict__ ew2,
    const void* __restrict__ nw1, const void* __restrict__ nw2,
    u16* __restrict__ packed, const int* __restrict__ flagp)
{
  const int isbf = *flagp;
  int t = blockIdx.x*256 + threadIdx.x;       // 24 * 2048
  int m = t >> 11; int r = t & 2047;
  int lane = r & 63; int ntk = r >> 6;
  int kk = ntk >> 3, nt = ntk & 7;
  int l = m/6, w = m%6;
  const void* src; long off;
  switch(w){
    case 0: src=ew1; off=(long)l*257*128;            break; // W1a
    case 1: src=ew1; off=(long)l*257*128 + 128*128;  break; // W1b
    case 2: src=ew2; off=(long)l*128*128;            break; // EW2
    case 3: src=nw1; off=(long)l*256*128;            break; // NW1a
    case 4: src=nw1; off=(long)l*256*128 + 128*128;  break; // NW1b
    default:src=nw2; off=(long)l*128*128;            break; // NW2
  }
  int c  = nt*16 + (lane & 15);
  int k0 = kk*32 + (lane >> 4)*8;
  u16 vals[8];
#pragma unroll
  for (int j=0;j<8;j++){
    long idx = off + (long)(k0+j)*128 + c;
    vals[j] = isbf ? ((const u16*)src)[idx] : f2b(((const float*)src)[idx]);
  }
  bf16x8 v; __builtin_memcpy(&v, vals, 16);
  *(bf16x8*)(packed + (long)t*8) = v;
}

// ---------- per-layer w2p = EW2 @ pw1[0:128], c2p = eb2 . pw1[0:128] ----------
__global__ __launch_bounds__(128) void w2p_kernel(
    const void* __restrict__ ew2, const void* __restrict__ eb2, const void* __restrict__ pw1,
    float* __restrict__ w2p, float* __restrict__ c2p, const int* __restrict__ flagp)
{
  const int isbf = *flagp;
  int l = blockIdx.x, i = threadIdx.x;
  long Woff = (long)l*128*128, poff = (long)l*129;
  float acc = 0.f;
  for (int j=0;j<128;j++) acc += ldf(ew2, Woff + (long)i*128 + j, isbf) * ldf(pw1, poff + j, isbf);
  w2p[l*128+i] = acc;
  __shared__ float red[128];
  red[i] = ldf(eb2, (long)l*128 + i, isbf) * ldf(pw1, poff + i, isbf);
  __syncthreads();
  for (int st=64; st>0; st>>=1){ if (i<st) red[i]+=red[i+st]; __syncthreads(); }
  if (i==0) c2p[l] = red[0];
}

// ---------- per-layer scalar params {pw1[128], pb1, pw2, pb2} ----------
__global__ void pparm_kernel(const void* pw1, const void* pb1, const void* pw2, const void* pb2,
                             float* pparm, const int* flagp)
{
  const int isbf = *flagp;
  int l = threadIdx.x;
  if (l < 4){
    pparm[l*4+0] = ldf(pw1, (long)l*129 + 128, isbf);
    pparm[l*4+1] = ldf(pb1, l, isbf);
    pparm[l*4+2] = ldf(pw2, l, isbf);
    pparm[l*4+3] = ldf(pb2, l, isbf);
  }
}

__global__ __launch_bounds__(256) void deg_kernel(const int* __restrict__ tgt, float* __restrict__ deg, int E){
  int i = blockIdx.x*256 + threadIdx.x;
  if (i < E) unsafeAtomicAdd(&deg[tgt[i]], 1.f);
}

// ---------- initial projection x = nf @ npw + npb ----------
__global__ __launch_bounds__(128) void proj_kernel(
    const void* __restrict__ nf, const void* __restrict__ W, const void* __restrict__ bvec,
    float* __restrict__ xf, u16* __restrict__ xb, int N, const int* __restrict__ flagp)
{
  const int isbf = *flagp;
  int n = blockIdx.x, d = threadIdx.x;
  if (n >= N) return;
  float acc = ldf(bvec, d, isbf);
#pragma unroll
  for (int f=0; f<12; f++) acc += ldf(nf, (long)n*12+f, isbf) * ldf(W, f*128+d, isbf);
  xf[(long)n*128+d] = acc;
  xb[(long)n*128+d] = f2b(acc);
}

__global__ __launch_bounds__(256) void cvtp_kernel(const void* __restrict__ pos, float* __restrict__ pf,
                                                   int n, const int* __restrict__ flagp){
  const int isbf = *flagp;
  int i = blockIdx.x*256 + threadIdx.x;
  if (i < n) pf[i] = ldf(pos, i, isbf);
}
__global__ __launch_bounds__(256) void axpy_kernel(float* __restrict__ p, const float* __restrict__ d, int n){
  int i = blockIdx.x*256 + threadIdx.x;
  if (i < n) p[i] += d[i];
}
__global__ __launch_bounds__(256) void conv_kernel(const float* __restrict__ in, u16* __restrict__ out, int n4){
  int i = blockIdx.x*256 + threadIdx.x;
  if (i >= n4) return;
  float4 v = *(const float4*)(in + (long)i*4);
  uint2 r;
  r.x = (unsigned)f2b(v.x) | ((unsigned)f2b(v.y)<<16);
  r.y = (unsigned)f2b(v.z) | ((unsigned)f2b(v.w)<<16);
  *(uint2*)(out + (long)i*4) = r;
}

// ---------- generic [N,128]@[128,128] bf16 MFMA matmul, no LDS ----------
template<int DUAL, int SILU, int RES, int DEGB, int BIAS>
__global__ __launch_bounds__(256) void mm128_kernel(
    const u16* __restrict__ X1, const u16* __restrict__ W1p,
    const u16* __restrict__ X2, const u16* __restrict__ W2p,
    const void* __restrict__ bias, long bias_off,
    const float* __restrict__ deg, const void* __restrict__ degb, long degb_off,
    float* __restrict__ resF, u16* __restrict__ outB, int nrows,
    const int* __restrict__ flagp)
{
  const int tid = threadIdx.x;
  const int wave = tid>>6, lane = tid&63;
  const int row0 = (blockIdx.x*4 + wave)*16;
  if (row0 >= nrows) return;
  const int isbf = (BIAS || DEGB) ? *flagp : 0;
  const int lr = lane&15, lg = lane>>4;
  floatx4 acc[8];
#pragma unroll
  for (int i=0;i<8;i++) acc[i] = (floatx4){0.f,0.f,0.f,0.f};
  int arow = row0 + lr; if (arow >= nrows) arow = nrows-1;
  {
    const u16* xr = X1 + (long)arow*128;
#pragma unroll
    for (int kk=0;kk<4;kk++){
      bf16x8 a = *(const bf16x8*)(xr + kk*32 + lg*8);
#pragma unroll
      for (int nt=0;nt<8;nt++){
        bf16x8 b = *(const bf16x8*)(W1p + ((kk*8+nt)*64 + lane)*8);
        acc[nt] = __builtin_amdgcn_mfma_f32_16x16x32_bf16(a, b, acc[nt], 0, 0, 0);
      }
    }
  }
  if (DUAL){
    const u16* xr = X2 + (long)arow*128;
#pragma unroll
    for (int kk=0;kk<4;kk++){
      bf16x8 a = *(const bf16x8*)(xr + kk*32 + lg*8);
#pragma unroll
      for (int nt=0;nt<8;nt++){
        bf16x8 b = *(const bf16x8*)(W2p + ((kk*8+nt)*64 + lane)*8);
        acc[nt] = __builtin_amdgcn_mfma_f32_16x16x32_bf16(a, b, acc[nt], 0, 0, 0);
      }
    }
  }
  // C/D layout: col = lane&15, row = (lane>>4)*4 + reg   [measured m89/m91]
#pragma unroll
  for (int r=0;r<4;r++){
    int row = row0 + lg*4 + r;
    if (row >= nrows) continue;
#pragma unroll
    for (int nt=0;nt<8;nt++){
      int col = nt*16 + lr;
      float v = acc[nt][r];
      if (BIAS) v += ldf(bias, bias_off + col, isbf);
      if (DEGB) v += deg[row] * ldf(degb, degb_off + col, isbf);
      if (SILU) v = siluf(v);
      if (RES){ float t = resF[(long)row*128+col] + v; resF[(long)row*128+col] = t; v = t; }
      outB[(long)row*128+col] = f2b(v);
    }
  }
}

// ---------- edge kernel: one wave per edge, 2 channels/lane ----------
__global__ __launch_bounds__(256) void edge_kernel(
    const int* __restrict__ src, const int* __restrict__ tgt,
    const float* __restrict__ pf,
    const u16* __restrict__ A, const u16* __restrict__ B,
    const void* __restrict__ ew1, long w1c_off,
    const float* __restrict__ w2p, const float* __restrict__ c2pl,
    const float* __restrict__ pp,
    float* __restrict__ Hagg, float* __restrict__ dp, int E,
    const int* __restrict__ flagp)
{
  const int isbf = *flagp;
  int gid = blockIdx.x*256 + threadIdx.x;
  int e = gid >> 6, lane = gid & 63;
  if (e >= E) return;
  int s = src[e], t = tgt[e];
  float2 ps = *(const float2*)(pf + 2*(long)s);
  float2 pt = *(const float2*)(pf + 2*(long)t);
  float dx = pt.x - ps.x, dy = pt.y - ps.y;
  float dist = sqrtf(dx*dx + dy*dy);
  unsigned av = *(const unsigned*)(A + (long)s*128 + 2*lane);
  unsigned bv = *(const unsigned*)(B + (long)t*128 + 2*lane);
  float c0 = ldf(ew1, w1c_off + 2*lane,     isbf);
  float c1 = ldf(ew1, w1c_off + 2*lane + 1, isbf);
  float h0 = b2f((u16)av)       + b2f((u16)bv)       + dist*c0;
  float h1 = b2f((u16)(av>>16)) + b2f((u16)(bv>>16)) + dist*c1;
  h0 = siluf(h0); h1 = siluf(h1);
  float* hrow = Hagg + (long)t*128;
  unsafeAtomicAdd(hrow + 2*lane,     h0);
  unsafeAtomicAdd(hrow + 2*lane + 1, h1);
  float2 wp = *(const float2*)(w2p + 2*lane);
  float part = h0*wp.x + h1*wp.y;
#pragma unroll
  for (int off=32; off; off>>=1) part += __shfl_down(part, off);
  if (lane == 0){
    float spre = part + c2pl[0] + dist*pp[0] + pp[1];
    float pwv  = siluf(spre)*pp[2] + pp[3];
    float inv  = 1.f/(dist + 1e-6f);
    unsafeAtomicAdd(dp + 2*(long)t,     dx*inv*pwv);
    unsafeAtomicAdd(dp + 2*(long)t + 1, dy*inv*pwv);
  }
}

// ---------- final layernorm, one wave per node ----------
__global__ __launch_bounds__(256) void ln_kernel(
    const float* __restrict__ xf, const void* __restrict__ g, const void* __restrict__ b,
    void* __restrict__ out, int N, const int* __restrict__ flagp)
{
  const int isbf = *flagp;
  int tid = threadIdx.x, lane = tid & 63;
  int n = blockIdx.x*4 + (tid>>6);
  if (n >= N) return;
  const float* xr = xf + (long)n*128;
  float x0 = xr[2*lane], x1 = xr[2*lane+1];
  float s = x0 + x1, q = x0*x0 + x1*x1;
#pragma unroll
  for (int off=32; off; off>>=1){ s += __shfl_xor(s, off); q += __shfl_xor(q, off); }
  float mu  = s * (1.f/128.f);
  float var = q * (1.f/128.f) - mu*mu;
  float inv = rsqrtf(var + 1e-5f);
  float y0 = (x0-mu)*inv*ldf(g,2*lane,isbf)   + ldf(b,2*lane,isbf);
  float y1 = (x1-mu)*inv*ldf(g,2*lane+1,isbf) + ldf(b,2*lane+1,isbf);
  if (isbf){
    unsigned pk = (unsigned)f2b(y0) | ((unsigned)f2b(y1)<<16);
    *(unsigned*)((u16*)out + (long)n*128 + 2*lane) = pk;
  } else {
    float2 v; v.x = y0; v.y = y1;
    *(float2*)((float*)out + (long)n*128 + 2*lane) = v;
  }
}

extern "C" void kernel_launch(void* const* d_in, const int* in_sizes, int n_in,
                              void* d_out, int out_size, void* d_ws, size_t ws_size,
                              hipStream_t stream)
{
  const void* nf  = d_in[0];
  const void* pos = d_in[1];
  const void* npw = d_in[3];
  const void* npb = d_in[4];
  const void* ew1 = d_in[7];
  const void* eb1 = d_in[8];
  const void* ew2 = d_in[9];
  const void* eb2 = d_in[10];
  const void* nw1 = d_in[11];
  const void* nb1 = d_in[12];
  const void* nw2 = d_in[13];
  const void* nb2 = d_in[14];
  const void* pw1 = d_in[15];
  const void* pb1 = d_in[16];
  const void* pw2 = d_in[17];
  const void* pb2 = d_in[18];
  const void* lng = d_in[19];
  const void* lnb = d_in[20];
  const int* eidx = (const int*)d_in[21];
  const int N = NNODES, E = NEDGES;
  const int* srcp = eidx;
  const int* tgtp = eidx + E;

  char* w = (char*)d_ws;
  size_t off = 0;
  auto alloc = [&](size_t bytes)->char* { char* p = w + off; off += (bytes + 255)/256*256; return p; };
  float* xf    = (float*)alloc((size_t)N*128*4);   // fp32 residual-stream master
  u16*   xb    = (u16*)  alloc((size_t)N*128*2);   // bf16 copy for MFMA
  u16*   Ab    = (u16*)  alloc((size_t)N*128*2);
  u16*   Bb    = (u16*)  alloc((size_t)N*128*2);
  float* Hagg  = (float*)alloc((size_t)N*128*4);   // fp32 atomic accumulator
  float* dp    = (float*)alloc((size_t)N*2*4);     // contiguous after Hagg (size mult of 256)
  float* pf    = (float*)alloc((size_t)N*2*4);
  float* deg   = (float*)alloc((size_t)N*4);
  u16*   pk    = (u16*)  alloc((size_t)24*16384*2);
  float* w2p   = (float*)alloc(4*128*4);
  float* c2p   = (float*)alloc(4*4);
  float* pparm = (float*)alloc(16*4);
  int*   flag  = (int*)  alloc(4);
  u16* Hb   = Ab;  // alias: Ab dead after edge_kernel
  u16* aggb = Bb;  // alias: Bb dead after edge_kernel (agg written after Hb read starts? no: DEGB reads Ab, writes Bb — ok)
  u16* hb   = Ab;  // alias: Ab(Hb) dead after DEGB mm

  detect_kernel<<<1, 64, 0, stream>>>(lng, flag);
  hipMemsetAsync(deg, 0, (size_t)N*4, stream);
  pack_kernel<<<192, 256, 0, stream>>>(ew1, ew2, nw1, nw2, pk, flag);
  w2p_kernel<<<4, 128, 0, stream>>>(ew2, eb2, pw1, w2p, c2p, flag);
  pparm_kernel<<<1, 64, 0, stream>>>(pw1, pb1, pw2, pb2, pparm, flag);
  deg_kernel<<<(E+255)/256, 256, 0, stream>>>(tgtp, deg, E);
  proj_kernel<<<N, 128, 0, stream>>>(nf, npw, npb, xf, xb, N, flag);
  cvtp_kernel<<<(2*N+255)/256, 256, 0, stream>>>(pos, pf, 2*N, flag);

  const int GMM = (N + 63)/64;
  for (int l = 0; l < 4; l++){
    const u16* W1a  = pk + (l*6+0)*16384;
    const u16* W1b  = pk + (l*6+1)*16384;
    const u16* EW2p = pk + (l*6+2)*16384;
    const u16* NW1a = pk + (l*6+3)*16384;
    const u16* NW1b = pk + (l*6+4)*16384;
    const u16* NW2p = pk + (l*6+5)*16384;

    // A = bf16(x@W1a + eb1), B = bf16(x@W1b)
    mm128_kernel<0,0,0,0,1><<<GMM,256,0,stream>>>(xb, W1a, nullptr, nullptr,
        eb1, (long)l*128, nullptr, nullptr, 0, nullptr, Ab, N, flag);
    mm128_kernel<0,0,0,0,0><<<GMM,256,0,stream>>>(xb, W1b, nullptr, nullptr,
        nullptr, 0, nullptr, nullptr, 0, nullptr, Bb, N, flag);
    hipMemsetAsync(Hagg, 0, (size_t)N*128*4 + (size_t)N*2*4, stream);  // Hagg + dp
    edge_kernel<<<(E*64)/256, 256, 0, stream>>>(
        srcp, tgtp, pf, Ab, Bb,
        ew1, (long)l*257*128 + 256*128,   // w1c row (element offset)
        w2p + l*128, c2p + l, pparm + l*4,
        Hagg, dp, E, flag);
    conv_kernel<<<(N*32+255)/256, 256, 0, stream>>>(Hagg, Hb, N*32);
    axpy_kernel<<<(2*N+255)/256, 256, 0, stream>>>(pf, dp, 2*N);
    // agg = bf16(Hb@EW2 + deg*eb2)
    mm128_kernel<0,0,0,1,0><<<GMM,256,0,stream>>>(Hb, EW2p, nullptr, nullptr,
        nullptr, 0, deg, eb2, (long)l*128, nullptr, aggb, N, flag);
    // hidden = bf16(silu(x@NW1a + agg@NW1b + nb1))
    mm128_kernel<1,1,0,0,1><<<GMM,256,0,stream>>>(xb, NW1a, aggb, NW1b,
        nb1, (long)l*128, nullptr, nullptr, 0, nullptr, hb, N, flag);
    // x += hidden@NW2 + nb2  (updates fp32 master and bf16 copy)
    mm128_kernel<0,0,1,0,1><<<GMM,256,0,stream>>>(hb, NW2p, nullptr, nullptr,
        nb2, (long)l*128, nullptr, nullptr, 0, xf, xb, N, flag);
  }
  ln_kernel<<<(N+3)/4, 256, 0, stream>>>(xf, lng, lnb, d_out, N, flag);
}

// Round 3
// 868.833 us; speedup vs baseline: 1.7322x; 1.7322x over previous
//
#include <hip/hip_runtime.h>
#include <hip/hip_bf16.h>

// EGNN encoder, N=50000, E=250000, D=128, L=4. bf16 inputs/output (verified R2).
// R3: CSR-by-tgt aggregation (no atomics), fused A/B matmul, EW2@NW1b folding.

#define NNODES 50000
#define NEDGES 250000

typedef unsigned short u16;
typedef __attribute__((ext_vector_type(8))) short bf16x8;
typedef __attribute__((ext_vector_type(4))) float floatx4;

__device__ __forceinline__ float b2f(u16 h){ unsigned u=((unsigned)h)<<16; float f; __builtin_memcpy(&f,&u,4); return f; }
__device__ __forceinline__ u16 f2b(float f){ unsigned u; __builtin_memcpy(&u,&f,4); u = u + 0x7FFFu + ((u>>16)&1u); return (u16)(u>>16); }
__device__ __forceinline__ float siluf(float x){ return x/(1.f+__expf(-x)); }
__device__ __forceinline__ float ldf(const void* p, long i, int isbf){
  return isbf ? b2f(((const u16*)p)[i]) : ((const float*)p)[i];
}

__global__ void detect_kernel(const void* lng, int* flag){
  if (threadIdx.x==0 && blockIdx.x==0) *flag = (((const u16*)lng)[0] != 0) ? 1 : 0;
}

// ---------- weight packing into MFMA B-fragment order (24 input matrices) ----------
__global__ __launch_bounds__(256) void pack_kernel(
    const void* __restrict__ ew1, const void* __restrict__ ew2,
    const void* __restrict__ nw1, const void* __restrict__ nw2,
    u16* __restrict__ packed, const int* __restrict__ flagp)
{
  const int isbf = *flagp;
  int t = blockIdx.x*256 + threadIdx.x;       // 24 * 2048
  int m = t >> 11; int r = t & 2047;
  int lane = r & 63; int ntk = r >> 6;
  int kk = ntk >> 3, nt = ntk & 7;
  int l = m/6, w = m%6;
  const void* src; long off;
  switch(w){
    case 0: src=ew1; off=(long)l*257*128;            break; // W1a
    case 1: src=ew1; off=(long)l*257*128 + 128*128;  break; // W1b
    case 2: src=ew2; off=(long)l*128*128;            break; // EW2 (unused in loop now, kept)
    case 3: src=nw1; off=(long)l*256*128;            break; // NW1a
    case 4: src=nw1; off=(long)l*256*128 + 128*128;  break; // NW1b (unused)
    default:src=nw2; off=(long)l*128*128;            break; // NW2
  }
  int c  = nt*16 + (lane & 15);
  int k0 = kk*32 + (lane >> 4)*8;
  u16 vals[8];
#pragma unroll
  for (int j=0;j<8;j++){
    long idx = off + (long)(k0+j)*128 + c;
    vals[j] = isbf ? ((const u16*)src)[idx] : f2b(((const float*)src)[idx]);
  }
  bf16x8 v; __builtin_memcpy(&v, vals, 16);
  *(bf16x8*)(packed + (long)t*8) = v;
}

// ---------- pack fp32 W12[l] (4 matrices) into chunks 24..27 ----------
__global__ __launch_bounds__(256) void pack2_kernel(
    const float* __restrict__ W12f, u16* __restrict__ packed)
{
  int t = blockIdx.x*256 + threadIdx.x;       // 4 * 2048
  int m = t >> 11; int r = t & 2047;
  int lane = r & 63; int ntk = r >> 6;
  int kk = ntk >> 3, nt = ntk & 7;
  const float* base = W12f + (long)m*16384;
  int c  = nt*16 + (lane & 15);
  int k0 = kk*32 + (lane >> 4)*8;
  u16 vals[8];
#pragma unroll
  for (int j=0;j<8;j++) vals[j] = f2b(base[(long)(k0+j)*128 + c]);
  bf16x8 v; __builtin_memcpy(&v, vals, 16);
  *(bf16x8*)(packed + ((long)(24+m)*2048 + r)*8) = v;
}

// ---------- W12[l][k][j] = sum_d EW2[l][k][d]*NW1b[l][d][j] (fp32) ----------
__global__ __launch_bounds__(128) void w12_kernel(
    const void* __restrict__ ew2, const void* __restrict__ nw1,
    float* __restrict__ W12f, const int* __restrict__ flagp)
{
  const int isbf = *flagp;
  int l = blockIdx.x >> 7, k = blockIdx.x & 127, j = threadIdx.x;
  long e2 = (long)l*16384 + (long)k*128;
  long nb = (long)l*256*128 + 128*128;
  float acc = 0.f;
  for (int d=0; d<128; d++)
    acc += ldf(ew2, e2 + d, isbf) * ldf(nw1, nb + (long)d*128 + j, isbf);
  W12f[(long)l*16384 + (long)k*128 + j] = acc;
}

// ---------- ebW[l][j] = sum_d eb2[l][d]*NW1b[l][d][j] ----------
__global__ __launch_bounds__(128) void ebw_kernel(
    const void* __restrict__ eb2, const void* __restrict__ nw1,
    float* __restrict__ ebW, const int* __restrict__ flagp)
{
  const int isbf = *flagp;
  int l = blockIdx.x, j = threadIdx.x;
  long nb = (long)l*256*128 + 128*128;
  float acc = 0.f;
  for (int d=0; d<128; d++)
    acc += ldf(eb2, (long)l*128 + d, isbf) * ldf(nw1, nb + (long)d*128 + j, isbf);
  ebW[l*128+j] = acc;
}

// ---------- per-layer w2p = EW2 @ pw1[0:128], c2p = eb2 . pw1[0:128] ----------
__global__ __launch_bounds__(128) void w2p_kernel(
    const void* __restrict__ ew2, const void* __restrict__ eb2, const void* __restrict__ pw1,
    float* __restrict__ w2p, float* __restrict__ c2p, const int* __restrict__ flagp)
{
  const int isbf = *flagp;
  int l = blockIdx.x, i = threadIdx.x;
  long Woff = (long)l*128*128, poff = (long)l*129;
  float acc = 0.f;
  for (int j=0;j<128;j++) acc += ldf(ew2, Woff + (long)i*128 + j, isbf) * ldf(pw1, poff + j, isbf);
  w2p[l*128+i] = acc;
  __shared__ float red[128];
  red[i] = ldf(eb2, (long)l*128 + i, isbf) * ldf(pw1, poff + i, isbf);
  __syncthreads();
  for (int st=64; st>0; st>>=1){ if (i<st) red[i]+=red[i+st]; __syncthreads(); }
  if (i==0) c2p[l] = red[0];
}

__global__ void pparm_kernel(const void* pw1, const void* pb1, const void* pw2, const void* pb2,
                             float* pparm, const int* flagp)
{
  const int isbf = *flagp;
  int l = threadIdx.x;
  if (l < 4){
    pparm[l*4+0] = ldf(pw1, (long)l*129 + 128, isbf);
    pparm[l*4+1] = ldf(pb1, l, isbf);
    pparm[l*4+2] = ldf(pw2, l, isbf);
    pparm[l*4+3] = ldf(pb2, l, isbf);
  }
}

// ---------- CSR build: histogram, scan, scatter ----------
__global__ __launch_bounds__(256) void hist_kernel(const int* __restrict__ tgt, int* __restrict__ cnt, int E){
  int i = blockIdx.x*256 + threadIdx.x;
  if (i < E) atomicAdd(&cnt[tgt[i]], 1);
}

__global__ __launch_bounds__(1024) void scan_kernel(
    const int* __restrict__ cnt, int* __restrict__ rowptr, int* __restrict__ cursor,
    float* __restrict__ degf, int N)
{
  __shared__ int lds[1024];
  int i = threadIdx.x;
  int chunk = (N + 1023)/1024;
  int base = i*chunk;
  int s = 0;
  for (int k=0;k<chunk;k++){ int idx=base+k; if (idx<N) s += cnt[idx]; }
  lds[i] = s; __syncthreads();
  for (int off=1; off<1024; off<<=1){
    int v = (i>=off) ? lds[i-off] : 0;
    __syncthreads();
    lds[i] += v;
    __syncthreads();
  }
  int run = lds[i] - s;   // exclusive prefix
  for (int k=0;k<chunk;k++){
    int idx = base+k;
    if (idx < N){
      int c = cnt[idx];
      rowptr[idx] = run; cursor[idx] = run; degf[idx] = (float)c;
      run += c;
    }
  }
  if (i == 1023) rowptr[N] = lds[1023];
}

__global__ __launch_bounds__(256) void scatter_kernel(
    const int* __restrict__ src, const int* __restrict__ tgt,
    int* __restrict__ cursor, int* __restrict__ permsrc, int E)
{
  int e = blockIdx.x*256 + threadIdx.x;
  if (e >= E) return;
  int t = tgt[e];
  int p = atomicAdd(&cursor[t], 1);
  permsrc[p] = src[e];
}

// ---------- initial projection x = nf @ npw + npb (2 nodes/block) ----------
__global__ __launch_bounds__(256) void proj_kernel(
    const void* __restrict__ nf, const void* __restrict__ W, const void* __restrict__ bvec,
    float* __restrict__ xf, u16* __restrict__ xb, int N, const int* __restrict__ flagp)
{
  const int isbf = *flagp;
  int n = blockIdx.x*2 + (threadIdx.x>>7), d = threadIdx.x & 127;
  if (n >= N) return;
  float acc = ldf(bvec, d, isbf);
#pragma unroll
  for (int f=0; f<12; f++) acc += ldf(nf, (long)n*12+f, isbf) * ldf(W, f*128+d, isbf);
  xf[(long)n*128+d] = acc;
  xb[(long)n*128+d] = f2b(acc);
}

__global__ __launch_bounds__(256) void cvtp_kernel(const void* __restrict__ pos, float* __restrict__ pf,
                                                   int n, const int* __restrict__ flagp){
  const int isbf = *flagp;
  int i = blockIdx.x*256 + threadIdx.x;
  if (i < n) pf[i] = ldf(pos, i, isbf);
}

// ---------- fused A/B matmul: Ab = bf16(x@W1a+eb1), Bb = bf16(x@W1b) ----------
__global__ __launch_bounds__(256) void mmab_kernel(
    const u16* __restrict__ X, const u16* __restrict__ Wa, const u16* __restrict__ Wb,
    const void* __restrict__ bias, long bias_off,
    u16* __restrict__ Ab, u16* __restrict__ Bb, int nrows, const int* __restrict__ flagp)
{
  const int tid = threadIdx.x;
  const int wave = tid>>6, lane = tid&63;
  const int row0 = (blockIdx.x*4 + wave)*16;
  if (row0 >= nrows) return;
  const int isbf = *flagp;
  const int lr = lane&15, lg = lane>>4;
  floatx4 accA[8], accB[8];
#pragma unroll
  for (int i=0;i<8;i++){ accA[i]=(floatx4){0,0,0,0}; accB[i]=(floatx4){0,0,0,0}; }
  int arow = row0 + lr; if (arow >= nrows) arow = nrows-1;
  const u16* xr = X + (long)arow*128;
#pragma unroll
  for (int kk=0;kk<4;kk++){
    bf16x8 a = *(const bf16x8*)(xr + kk*32 + lg*8);
#pragma unroll
    for (int nt=0;nt<8;nt++){
      bf16x8 ba = *(const bf16x8*)(Wa + ((kk*8+nt)*64 + lane)*8);
      accA[nt] = __builtin_amdgcn_mfma_f32_16x16x32_bf16(a, ba, accA[nt], 0, 0, 0);
      bf16x8 bb = *(const bf16x8*)(Wb + ((kk*8+nt)*64 + lane)*8);
      accB[nt] = __builtin_amdgcn_mfma_f32_16x16x32_bf16(a, bb, accB[nt], 0, 0, 0);
    }
  }
#pragma unroll
  for (int r=0;r<4;r++){
    int row = row0 + lg*4 + r;
    if (row >= nrows) continue;
#pragma unroll
    for (int nt=0;nt<8;nt++){
      int col = nt*16 + lr;
      Ab[(long)row*128+col] = f2b(accA[nt][r] + ldf(bias, bias_off + col, isbf));
      Bb[(long)row*128+col] = f2b(accB[nt][r]);
    }
  }
}

// ---------- generic [N,128]@[128,128] bf16 MFMA matmul ----------
template<int DUAL, int SILU, int RES, int FDEG, int BIAS>
__global__ __launch_bounds__(256) void mm128_kernel(
    const u16* __restrict__ X1, const u16* __restrict__ W1p,
    const u16* __restrict__ X2, const u16* __restrict__ W2p,
    const void* __restrict__ bias, long bias_off,
    const float* __restrict__ degf, const float* __restrict__ fdegb,
    float* __restrict__ resF, u16* __restrict__ outB, int nrows,
    const int* __restrict__ flagp)
{
  const int tid = threadIdx.x;
  const int wave = tid>>6, lane = tid&63;
  const int row0 = (blockIdx.x*4 + wave)*16;
  if (row0 >= nrows) return;
  const int isbf = BIAS ? *flagp : 0;
  const int lr = lane&15, lg = lane>>4;
  floatx4 acc[8];
#pragma unroll
  for (int i=0;i<8;i++) acc[i] = (floatx4){0.f,0.f,0.f,0.f};
  int arow = row0 + lr; if (arow >= nrows) arow = nrows-1;
  {
    const u16* xr = X1 + (long)arow*128;
#pragma unroll
    for (int kk=0;kk<4;kk++){
      bf16x8 a = *(const bf16x8*)(xr + kk*32 + lg*8);
#pragma unroll
      for (int nt=0;nt<8;nt++){
        bf16x8 b = *(const bf16x8*)(W1p + ((kk*8+nt)*64 + lane)*8);
        acc[nt] = __builtin_amdgcn_mfma_f32_16x16x32_bf16(a, b, acc[nt], 0, 0, 0);
      }
    }
  }
  if (DUAL){
    const u16* xr = X2 + (long)arow*128;
#pragma unroll
    for (int kk=0;kk<4;kk++){
      bf16x8 a = *(const bf16x8*)(xr + kk*32 + lg*8);
#pragma unroll
      for (int nt=0;nt<8;nt++){
        bf16x8 b = *(const bf16x8*)(W2p + ((kk*8+nt)*64 + lane)*8);
        acc[nt] = __builtin_amdgcn_mfma_f32_16x16x32_bf16(a, b, acc[nt], 0, 0, 0);
      }
    }
  }
  // C/D layout: col = lane&15, row = (lane>>4)*4 + reg
#pragma unroll
  for (int r=0;r<4;r++){
    int row = row0 + lg*4 + r;
    if (row >= nrows) continue;
#pragma unroll
    for (int nt=0;nt<8;nt++){
      int col = nt*16 + lr;
      float v = acc[nt][r];
      if (BIAS) v += ldf(bias, bias_off + col, isbf);
      if (FDEG) v += degf[row] * fdegb[col];
      if (SILU) v = siluf(v);
      if (RES){ float t = resF[(long)row*128+col] + v; resF[(long)row*128+col] = t; v = t; }
      outB[(long)row*128+col] = f2b(v);
    }
  }
}

// ---------- CSR aggregation: one wave per target node, no atomics ----------
__global__ __launch_bounds__(256) void agg_kernel(
    const int* __restrict__ rowptr, const int* __restrict__ permsrc,
    const float* __restrict__ pf_in,
    const u16* __restrict__ A, const u16* __restrict__ B,
    const void* __restrict__ ew1, long w1c_off,
    const float* __restrict__ w2p, const float* __restrict__ c2pl,
    const float* __restrict__ pp,
    u16* __restrict__ Hb, float* __restrict__ pf_out, int N,
    const int* __restrict__ flagp)
{
  const int isbf = *flagp;
  int tid = threadIdx.x, lane = tid & 63;
  int t = blockIdx.x*4 + (tid>>6);
  if (t >= N) return;
  float c0 = ldf(ew1, w1c_off + 2*lane,     isbf);
  float c1 = ldf(ew1, w1c_off + 2*lane + 1, isbf);
  float2 wp = *(const float2*)(w2p + 2*lane);
  float c2 = c2pl[0];
  float p0 = pp[0], p1 = pp[1], p2 = pp[2], p3 = pp[3];
  int jb = rowptr[t], je = rowptr[t+1];
  float2 pt = *(const float2*)(pf_in + 2*(long)t);
  unsigned bv = *(const unsigned*)(B + (long)t*128 + 2*lane);
  float b0 = b2f((u16)bv), b1 = b2f((u16)(bv>>16));
  float h0a = 0.f, h1a = 0.f, dpx = 0.f, dpy = 0.f;
  for (int j = jb; j < je; j++){
    int s = permsrc[j];
    float2 ps = *(const float2*)(pf_in + 2*(long)s);
    float dx = pt.x - ps.x, dy = pt.y - ps.y;
    float dist = sqrtf(dx*dx + dy*dy);
    unsigned av = *(const unsigned*)(A + (long)s*128 + 2*lane);
    float h0 = siluf(b2f((u16)av)       + b0 + dist*c0);
    float h1 = siluf(b2f((u16)(av>>16)) + b1 + dist*c1);
    h0a += h0; h1a += h1;
    float part = h0*wp.x + h1*wp.y;
#pragma unroll
    for (int off=32; off; off>>=1) part += __shfl_xor(part, off);
    float spre = part + c2 + dist*p0 + p1;
    float pwv  = siluf(spre)*p2 + p3;
    float inv  = 1.f/(dist + 1e-6f);
    dpx += dx*inv*pwv; dpy += dy*inv*pwv;
  }
  *(unsigned*)(Hb + (long)t*128 + 2*lane) = (unsigned)f2b(h0a) | ((unsigned)f2b(h1a)<<16);
  if (lane == 0){
    float2 o; o.x = pt.x + dpx; o.y = pt.y + dpy;
    *(float2*)(pf_out + 2*(long)t) = o;
  }
}

// ---------- final layernorm, one wave per node ----------
__global__ __launch_bounds__(256) void ln_kernel(
    const float* __restrict__ xf, const void* __restrict__ g, const void* __restrict__ b,
    void* __restrict__ out, int N, const int* __restrict__ flagp)
{
  const int isbf = *flagp;
  int tid = threadIdx.x, lane = tid & 63;
  int n = blockIdx.x*4 + (tid>>6);
  if (n >= N) return;
  const float* xr = xf + (long)n*128;
  float x0 = xr[2*lane], x1 = xr[2*lane+1];
  float s = x0 + x1, q = x0*x0 + x1*x1;
#pragma unroll
  for (int off=32; off; off>>=1){ s += __shfl_xor(s, off); q += __shfl_xor(q, off); }
  float mu  = s * (1.f/128.f);
  float var = q * (1.f/128.f) - mu*mu;
  float inv = rsqrtf(var + 1e-5f);
  float y0 = (x0-mu)*inv*ldf(g,2*lane,isbf)   + ldf(b,2*lane,isbf);
  float y1 = (x1-mu)*inv*ldf(g,2*lane+1,isbf) + ldf(b,2*lane+1,isbf);
  if (isbf){
    unsigned pk = (unsigned)f2b(y0) | ((unsigned)f2b(y1)<<16);
    *(unsigned*)((u16*)out + (long)n*128 + 2*lane) = pk;
  } else {
    float2 v; v.x = y0; v.y = y1;
    *(float2*)((float*)out + (long)n*128 + 2*lane) = v;
  }
}

extern "C" void kernel_launch(void* const* d_in, const int* in_sizes, int n_in,
                              void* d_out, int out_size, void* d_ws, size_t ws_size,
                              hipStream_t stream)
{
  const void* nf  = d_in[0];
  const void* pos = d_in[1];
  const void* npw = d_in[3];
  const void* npb = d_in[4];
  const void* ew1 = d_in[7];
  const void* eb1 = d_in[8];
  const void* ew2 = d_in[9];
  const void* eb2 = d_in[10];
  const void* nw1 = d_in[11];
  const void* nb1 = d_in[12];
  const void* nw2 = d_in[13];
  const void* nb2 = d_in[14];
  const void* pw1 = d_in[15];
  const void* pb1 = d_in[16];
  const void* pw2 = d_in[17];
  const void* pb2 = d_in[18];
  const void* lng = d_in[19];
  const void* lnb = d_in[20];
  const int* eidx = (const int*)d_in[21];
  const int N = NNODES, E = NEDGES;
  const int* srcp = eidx;
  const int* tgtp = eidx + E;

  char* w = (char*)d_ws;
  size_t off = 0;
  auto alloc = [&](size_t bytes)->char* { char* p = w + off; off += (bytes + 255)/256*256; return p; };
  float* xf    = (float*)alloc((size_t)N*128*4);
  u16*   xb    = (u16*)  alloc((size_t)N*128*2);
  u16*   Ab    = (u16*)  alloc((size_t)N*128*2);
  u16*   Bb    = (u16*)  alloc((size_t)N*128*2);
  u16*   Hb    = (u16*)  alloc((size_t)N*128*2);
  float* pf0   = (float*)alloc((size_t)N*2*4);
  float* pf1   = (float*)alloc((size_t)N*2*4);
  int*   cnt   = (int*)  alloc((size_t)N*4);
  int*   rowptr= (int*)  alloc((size_t)(N+1)*4);
  int*   cursor= (int*)  alloc((size_t)N*4);
  float* degf  = (float*)alloc((size_t)N*4);
  int*   perm  = (int*)  alloc((size_t)E*4);
  u16*   pk    = (u16*)  alloc((size_t)28*16384*2);
  float* W12f  = (float*)alloc((size_t)4*16384*4);
  float* ebW   = (float*)alloc(4*128*4);
  float* w2p   = (float*)alloc(4*128*4);
  float* c2p   = (float*)alloc(4*4);
  float* pparm = (float*)alloc(16*4);
  int*   flag  = (int*)  alloc(4);
  u16* hb = Ab;   // Ab dead after agg_kernel

  detect_kernel<<<1, 64, 0, stream>>>(lng, flag);
  hipMemsetAsync(cnt, 0, (size_t)N*4, stream);
  hist_kernel<<<(E+255)/256, 256, 0, stream>>>(tgtp, cnt, E);
  scan_kernel<<<1, 1024, 0, stream>>>(cnt, rowptr, cursor, degf, N);
  scatter_kernel<<<(E+255)/256, 256, 0, stream>>>(srcp, tgtp, cursor, perm, E);
  pack_kernel<<<192, 256, 0, stream>>>(ew1, ew2, nw1, nw2, pk, flag);
  w12_kernel<<<512, 128, 0, stream>>>(ew2, nw1, W12f, flag);
  ebw_kernel<<<4, 128, 0, stream>>>(eb2, nw1, ebW, flag);
  pack2_kernel<<<32, 256, 0, stream>>>(W12f, pk);
  w2p_kernel<<<4, 128, 0, stream>>>(ew2, eb2, pw1, w2p, c2p, flag);
  pparm_kernel<<<1, 64, 0, stream>>>(pw1, pb1, pw2, pb2, pparm, flag);
  proj_kernel<<<(N+1)/2, 256, 0, stream>>>(nf, npw, npb, xf, xb, N, flag);
  cvtp_kernel<<<(2*N+255)/256, 256, 0, stream>>>(pos, pf0, 2*N, flag);

  const int GMM = (N + 63)/64;
  for (int l = 0; l < 4; l++){
    const u16* W1a  = pk + (l*6+0)*16384;
    const u16* W1b  = pk + (l*6+1)*16384;
    const u16* NW1a = pk + (l*6+3)*16384;
    const u16* NW2p = pk + (l*6+5)*16384;
    const u16* W12p = pk + (24+l)*16384;
    float* pin  = (l & 1) ? pf1 : pf0;
    float* pout = (l & 1) ? pf0 : pf1;

    mmab_kernel<<<GMM,256,0,stream>>>(xb, W1a, W1b, eb1, (long)l*128, Ab, Bb, N, flag);
    agg_kernel<<<(N+3)/4, 256, 0, stream>>>(
        rowptr, perm, pin, Ab, Bb,
        ew1, (long)l*257*128 + 256*128,
        w2p + l*128, c2p + l, pparm + l*4,
        Hb, pout, N, flag);
    // hidden = silu(x@NW1a + Hb@(EW2@NW1b) + deg*(eb2@NW1b) + nb1)
    mm128_kernel<1,1,0,1,1><<<GMM,256,0,stream>>>(xb, NW1a, Hb, W12p,
        nb1, (long)l*128, degf, ebW + l*128, nullptr, hb, N, flag);
    // x += hidden@NW2 + nb2
    mm128_kernel<0,0,1,0,1><<<GMM,256,0,stream>>>(hb, NW2p, nullptr, nullptr,
        nb2, (long)l*128, nullptr, nullptr, xf, xb, N, flag);
  }
  ln_kernel<<<(N+3)/4, 256, 0, stream>>>(xf, lng, lnb, d_out, N, flag);
}

// Round 4
// 736.549 us; speedup vs baseline: 2.0433x; 1.1796x over previous
//
#include <hip/hip_runtime.h>
#include <hip/hip_bf16.h>

// EGNN encoder, N=50000, E=250000, D=128, L=4. bf16 inputs/output (verified R2).
// R3: CSR-by-tgt aggregation (no atomics), fused A/B matmul, EW2@NW1b folding.
// R4: 3-stage parallel CSR scan (replaces 149us single-block scan).

#define NNODES 50000
#define NEDGES 250000

typedef unsigned short u16;
typedef __attribute__((ext_vector_type(8))) short bf16x8;
typedef __attribute__((ext_vector_type(4))) float floatx4;

__device__ __forceinline__ float b2f(u16 h){ unsigned u=((unsigned)h)<<16; float f; __builtin_memcpy(&f,&u,4); return f; }
__device__ __forceinline__ u16 f2b(float f){ unsigned u; __builtin_memcpy(&u,&f,4); u = u + 0x7FFFu + ((u>>16)&1u); return (u16)(u>>16); }
__device__ __forceinline__ float siluf(float x){ return x/(1.f+__expf(-x)); }
__device__ __forceinline__ float ldf(const void* p, long i, int isbf){
  return isbf ? b2f(((const u16*)p)[i]) : ((const float*)p)[i];
}

__global__ void detect_kernel(const void* lng, int* flag){
  if (threadIdx.x==0 && blockIdx.x==0) *flag = (((const u16*)lng)[0] != 0) ? 1 : 0;
}

// ---------- weight packing into MFMA B-fragment order (24 input matrices) ----------
__global__ __launch_bounds__(256) void pack_kernel(
    const void* __restrict__ ew1, const void* __restrict__ ew2,
    const void* __restrict__ nw1, const void* __restrict__ nw2,
    u16* __restrict__ packed, const int* __restrict__ flagp)
{
  const int isbf = *flagp;
  int t = blockIdx.x*256 + threadIdx.x;       // 24 * 2048
  int m = t >> 11; int r = t & 2047;
  int lane = r & 63; int ntk = r >> 6;
  int kk = ntk >> 3, nt = ntk & 7;
  int l = m/6, w = m%6;
  const void* src; long off;
  switch(w){
    case 0: src=ew1; off=(long)l*257*128;            break; // W1a
    case 1: src=ew1; off=(long)l*257*128 + 128*128;  break; // W1b
    case 2: src=ew2; off=(long)l*128*128;            break; // EW2
    case 3: src=nw1; off=(long)l*256*128;            break; // NW1a
    case 4: src=nw1; off=(long)l*256*128 + 128*128;  break; // NW1b
    default:src=nw2; off=(long)l*128*128;            break; // NW2
  }
  int c  = nt*16 + (lane & 15);
  int k0 = kk*32 + (lane >> 4)*8;
  u16 vals[8];
#pragma unroll
  for (int j=0;j<8;j++){
    long idx = off + (long)(k0+j)*128 + c;
    vals[j] = isbf ? ((const u16*)src)[idx] : f2b(((const float*)src)[idx]);
  }
  bf16x8 v; __builtin_memcpy(&v, vals, 16);
  *(bf16x8*)(packed + (long)t*8) = v;
}

// ---------- pack fp32 W12[l] (4 matrices) into chunks 24..27 ----------
__global__ __launch_bounds__(256) void pack2_kernel(
    const float* __restrict__ W12f, u16* __restrict__ packed)
{
  int t = blockIdx.x*256 + threadIdx.x;       // 4 * 2048
  int m = t >> 11; int r = t & 2047;
  int lane = r & 63; int ntk = r >> 6;
  int kk = ntk >> 3, nt = ntk & 7;
  const float* base = W12f + (long)m*16384;
  int c  = nt*16 + (lane & 15);
  int k0 = kk*32 + (lane >> 4)*8;
  u16 vals[8];
#pragma unroll
  for (int j=0;j<8;j++) vals[j] = f2b(base[(long)(k0+j)*128 + c]);
  bf16x8 v; __builtin_memcpy(&v, vals, 16);
  *(bf16x8*)(packed + ((long)(24+m)*2048 + r)*8) = v;
}

// ---------- W12[l][k][j] = sum_d EW2[l][k][d]*NW1b[l][d][j] (fp32) ----------
__global__ __launch_bounds__(128) void w12_kernel(
    const void* __restrict__ ew2, const void* __restrict__ nw1,
    float* __restrict__ W12f, const int* __restrict__ flagp)
{
  const int isbf = *flagp;
  int l = blockIdx.x >> 7, k = blockIdx.x & 127, j = threadIdx.x;
  long e2 = (long)l*16384 + (long)k*128;
  long nb = (long)l*256*128 + 128*128;
  float acc = 0.f;
  for (int d=0; d<128; d++)
    acc += ldf(ew2, e2 + d, isbf) * ldf(nw1, nb + (long)d*128 + j, isbf);
  W12f[(long)l*16384 + (long)k*128 + j] = acc;
}

// ---------- ebW[l][j] = sum_d eb2[l][d]*NW1b[l][d][j] ----------
__global__ __launch_bounds__(128) void ebw_kernel(
    const void* __restrict__ eb2, const void* __restrict__ nw1,
    float* __restrict__ ebW, const int* __restrict__ flagp)
{
  const int isbf = *flagp;
  int l = blockIdx.x, j = threadIdx.x;
  long nb = (long)l*256*128 + 128*128;
  float acc = 0.f;
  for (int d=0; d<128; d++)
    acc += ldf(eb2, (long)l*128 + d, isbf) * ldf(nw1, nb + (long)d*128 + j, isbf);
  ebW[l*128+j] = acc;
}

// ---------- per-layer w2p = EW2 @ pw1[0:128], c2p = eb2 . pw1[0:128] ----------
__global__ __launch_bounds__(128) void w2p_kernel(
    const void* __restrict__ ew2, const void* __restrict__ eb2, const void* __restrict__ pw1,
    float* __restrict__ w2p, float* __restrict__ c2p, const int* __restrict__ flagp)
{
  const int isbf = *flagp;
  int l = blockIdx.x, i = threadIdx.x;
  long Woff = (long)l*128*128, poff = (long)l*129;
  float acc = 0.f;
  for (int j=0;j<128;j++) acc += ldf(ew2, Woff + (long)i*128 + j, isbf) * ldf(pw1, poff + j, isbf);
  w2p[l*128+i] = acc;
  __shared__ float red[128];
  red[i] = ldf(eb2, (long)l*128 + i, isbf) * ldf(pw1, poff + i, isbf);
  __syncthreads();
  for (int st=64; st>0; st>>=1){ if (i<st) red[i]+=red[i+st]; __syncthreads(); }
  if (i==0) c2p[l] = red[0];
}

__global__ void pparm_kernel(const void* pw1, const void* pb1, const void* pw2, const void* pb2,
                             float* pparm, const int* flagp)
{
  const int isbf = *flagp;
  int l = threadIdx.x;
  if (l < 4){
    pparm[l*4+0] = ldf(pw1, (long)l*129 + 128, isbf);
    pparm[l*4+1] = ldf(pb1, l, isbf);
    pparm[l*4+2] = ldf(pw2, l, isbf);
    pparm[l*4+3] = ldf(pb2, l, isbf);
  }
}

// ---------- CSR build: histogram, 3-stage scan, scatter ----------
__global__ __launch_bounds__(256) void hist_kernel(const int* __restrict__ tgt, int* __restrict__ cnt, int E){
  int i = blockIdx.x*256 + threadIdx.x;
  if (i < E) atomicAdd(&cnt[tgt[i]], 1);
}

// stage A: per-block (256 counts) sum
__global__ __launch_bounds__(256) void bsum_kernel(const int* __restrict__ cnt, int* __restrict__ bsum, int N){
  int i = blockIdx.x*256 + threadIdx.x;
  int v = (i < N) ? cnt[i] : 0;
#pragma unroll
  for (int off=32; off; off>>=1) v += __shfl_down(v, off);
  __shared__ int ws[4];
  if ((threadIdx.x & 63) == 0) ws[threadIdx.x>>6] = v;
  __syncthreads();
  if (threadIdx.x == 0) bsum[blockIdx.x] = ws[0]+ws[1]+ws[2]+ws[3];
}

// stage B: single-block exclusive scan of nb (<=256) block sums, in place
__global__ __launch_bounds__(256) void bscan_kernel(int* __restrict__ bsum, int nb){
  __shared__ int lds[256];
  int i = threadIdx.x;
  int v = (i < nb) ? bsum[i] : 0;
  lds[i] = v; __syncthreads();
#pragma unroll
  for (int off=1; off<256; off<<=1){
    int t = (i>=off)? lds[i-off] : 0; __syncthreads();
    lds[i] += t; __syncthreads();
  }
  if (i < nb) bsum[i] = lds[i] - v;  // exclusive prefix
}

// stage C: per-block LDS scan + block offset -> rowptr/cursor/degf
__global__ __launch_bounds__(256) void csr_kernel(
    const int* __restrict__ cnt, const int* __restrict__ bsum,
    int* __restrict__ rowptr, int* __restrict__ cursor, float* __restrict__ degf, int N)
{
  __shared__ int lds[256];
  int i = blockIdx.x*256 + threadIdx.x;
  int c = (i < N) ? cnt[i] : 0;
  lds[threadIdx.x] = c; __syncthreads();
#pragma unroll
  for (int off=1; off<256; off<<=1){
    int t = (threadIdx.x>=off)? lds[threadIdx.x-off] : 0; __syncthreads();
    lds[threadIdx.x] += t; __syncthreads();
  }
  int run = bsum[blockIdx.x] + lds[threadIdx.x] - c;  // exclusive
  if (i < N){
    rowptr[i] = run; cursor[i] = run; degf[i] = (float)c;
    if (i == N-1) rowptr[N] = run + c;
  }
}

__global__ __launch_bounds__(256) void scatter_kernel(
    const int* __restrict__ src, const int* __restrict__ tgt,
    int* __restrict__ cursor, int* __restrict__ permsrc, int E)
{
  int e = blockIdx.x*256 + threadIdx.x;
  if (e >= E) return;
  int t = tgt[e];
  int p = atomicAdd(&cursor[t], 1);
  permsrc[p] = src[e];
}

// ---------- initial projection x = nf @ npw + npb (2 nodes/block) ----------
__global__ __launch_bounds__(256) void proj_kernel(
    const void* __restrict__ nf, const void* __restrict__ W, const void* __restrict__ bvec,
    float* __restrict__ xf, u16* __restrict__ xb, int N, const int* __restrict__ flagp)
{
  const int isbf = *flagp;
  int n = blockIdx.x*2 + (threadIdx.x>>7), d = threadIdx.x & 127;
  if (n >= N) return;
  float acc = ldf(bvec, d, isbf);
#pragma unroll
  for (int f=0; f<12; f++) acc += ldf(nf, (long)n*12+f, isbf) * ldf(W, f*128+d, isbf);
  xf[(long)n*128+d] = acc;
  xb[(long)n*128+d] = f2b(acc);
}

__global__ __launch_bounds__(256) void cvtp_kernel(const void* __restrict__ pos, float* __restrict__ pf,
                                                   int n, const int* __restrict__ flagp){
  const int isbf = *flagp;
  int i = blockIdx.x*256 + threadIdx.x;
  if (i < n) pf[i] = ldf(pos, i, isbf);
}

// ---------- fused A/B matmul: Ab = bf16(x@W1a+eb1), Bb = bf16(x@W1b) ----------
__global__ __launch_bounds__(256) void mmab_kernel(
    const u16* __restrict__ X, const u16* __restrict__ Wa, const u16* __restrict__ Wb,
    const void* __restrict__ bias, long bias_off,
    u16* __restrict__ Ab, u16* __restrict__ Bb, int nrows, const int* __restrict__ flagp)
{
  const int tid = threadIdx.x;
  const int wave = tid>>6, lane = tid&63;
  const int row0 = (blockIdx.x*4 + wave)*16;
  if (row0 >= nrows) return;
  const int isbf = *flagp;
  const int lr = lane&15, lg = lane>>4;
  floatx4 accA[8], accB[8];
#pragma unroll
  for (int i=0;i<8;i++){ accA[i]=(floatx4){0,0,0,0}; accB[i]=(floatx4){0,0,0,0}; }
  int arow = row0 + lr; if (arow >= nrows) arow = nrows-1;
  const u16* xr = X + (long)arow*128;
#pragma unroll
  for (int kk=0;kk<4;kk++){
    bf16x8 a = *(const bf16x8*)(xr + kk*32 + lg*8);
#pragma unroll
    for (int nt=0;nt<8;nt++){
      bf16x8 ba = *(const bf16x8*)(Wa + ((kk*8+nt)*64 + lane)*8);
      accA[nt] = __builtin_amdgcn_mfma_f32_16x16x32_bf16(a, ba, accA[nt], 0, 0, 0);
      bf16x8 bb = *(const bf16x8*)(Wb + ((kk*8+nt)*64 + lane)*8);
      accB[nt] = __builtin_amdgcn_mfma_f32_16x16x32_bf16(a, bb, accB[nt], 0, 0, 0);
    }
  }
#pragma unroll
  for (int r=0;r<4;r++){
    int row = row0 + lg*4 + r;
    if (row >= nrows) continue;
#pragma unroll
    for (int nt=0;nt<8;nt++){
      int col = nt*16 + lr;
      Ab[(long)row*128+col] = f2b(accA[nt][r] + ldf(bias, bias_off + col, isbf));
      Bb[(long)row*128+col] = f2b(accB[nt][r]);
    }
  }
}

// ---------- generic [N,128]@[128,128] bf16 MFMA matmul ----------
template<int DUAL, int SILU, int RES, int FDEG, int BIAS>
__global__ __launch_bounds__(256) void mm128_kernel(
    const u16* __restrict__ X1, const u16* __restrict__ W1p,
    const u16* __restrict__ X2, const u16* __restrict__ W2p,
    const void* __restrict__ bias, long bias_off,
    const float* __restrict__ degf, const float* __restrict__ fdegb,
    float* __restrict__ resF, u16* __restrict__ outB, int nrows,
    const int* __restrict__ flagp)
{
  const int tid = threadIdx.x;
  const int wave = tid>>6, lane = tid&63;
  const int row0 = (blockIdx.x*4 + wave)*16;
  if (row0 >= nrows) return;
  const int isbf = BIAS ? *flagp : 0;
  const int lr = lane&15, lg = lane>>4;
  floatx4 acc[8];
#pragma unroll
  for (int i=0;i<8;i++) acc[i] = (floatx4){0.f,0.f,0.f,0.f};
  int arow = row0 + lr; if (arow >= nrows) arow = nrows-1;
  {
    const u16* xr = X1 + (long)arow*128;
#pragma unroll
    for (int kk=0;kk<4;kk++){
      bf16x8 a = *(const bf16x8*)(xr + kk*32 + lg*8);
#pragma unroll
      for (int nt=0;nt<8;nt++){
        bf16x8 b = *(const bf16x8*)(W1p + ((kk*8+nt)*64 + lane)*8);
        acc[nt] = __builtin_amdgcn_mfma_f32_16x16x32_bf16(a, b, acc[nt], 0, 0, 0);
      }
    }
  }
  if (DUAL){
    const u16* xr = X2 + (long)arow*128;
#pragma unroll
    for (int kk=0;kk<4;kk++){
      bf16x8 a = *(const bf16x8*)(xr + kk*32 + lg*8);
#pragma unroll
      for (int nt=0;nt<8;nt++){
        bf16x8 b = *(const bf16x8*)(W2p + ((kk*8+nt)*64 + lane)*8);
        acc[nt] = __builtin_amdgcn_mfma_f32_16x16x32_bf16(a, b, acc[nt], 0, 0, 0);
      }
    }
  }
  // C/D layout: col = lane&15, row = (lane>>4)*4 + reg
#pragma unroll
  for (int r=0;r<4;r++){
    int row = row0 + lg*4 + r;
    if (row >= nrows) continue;
#pragma unroll
    for (int nt=0;nt<8;nt++){
      int col = nt*16 + lr;
      float v = acc[nt][r];
      if (BIAS) v += ldf(bias, bias_off + col, isbf);
      if (FDEG) v += degf[row] * fdegb[col];
      if (SILU) v = siluf(v);
      if (RES){ float t = resF[(long)row*128+col] + v; resF[(long)row*128+col] = t; v = t; }
      outB[(long)row*128+col] = f2b(v);
    }
  }
}

// ---------- CSR aggregation: one wave per target node, no atomics ----------
__global__ __launch_bounds__(256) void agg_kernel(
    const int* __restrict__ rowptr, const int* __restrict__ permsrc,
    const float* __restrict__ pf_in,
    const u16* __restrict__ A, const u16* __restrict__ B,
    const void* __restrict__ ew1, long w1c_off,
    const float* __restrict__ w2p, const float* __restrict__ c2pl,
    const float* __restrict__ pp,
    u16* __restrict__ Hb, float* __restrict__ pf_out, int N,
    const int* __restrict__ flagp)
{
  const int isbf = *flagp;
  int tid = threadIdx.x, lane = tid & 63;
  int t = blockIdx.x*4 + (tid>>6);
  if (t >= N) return;
  float c0 = ldf(ew1, w1c_off + 2*lane,     isbf);
  float c1 = ldf(ew1, w1c_off + 2*lane + 1, isbf);
  float2 wp = *(const float2*)(w2p + 2*lane);
  float c2 = c2pl[0];
  float p0 = pp[0], p1 = pp[1], p2 = pp[2], p3 = pp[3];
  int jb = rowptr[t], je = rowptr[t+1];
  float2 pt = *(const float2*)(pf_in + 2*(long)t);
  unsigned bv = *(const unsigned*)(B + (long)t*128 + 2*lane);
  float b0 = b2f((u16)bv), b1 = b2f((u16)(bv>>16));
  float h0a = 0.f, h1a = 0.f, dpx = 0.f, dpy = 0.f;
  for (int j = jb; j < je; j++){
    int s = permsrc[j];
    float2 ps = *(const float2*)(pf_in + 2*(long)s);
    float dx = pt.x - ps.x, dy = pt.y - ps.y;
    float dist = sqrtf(dx*dx + dy*dy);
    unsigned av = *(const unsigned*)(A + (long)s*128 + 2*lane);
    float h0 = siluf(b2f((u16)av)       + b0 + dist*c0);
    float h1 = siluf(b2f((u16)(av>>16)) + b1 + dist*c1);
    h0a += h0; h1a += h1;
    float part = h0*wp.x + h1*wp.y;
#pragma unroll
    for (int off=32; off; off>>=1) part += __shfl_xor(part, off);
    float spre = part + c2 + dist*p0 + p1;
    float pwv  = siluf(spre)*p2 + p3;
    float inv  = 1.f/(dist + 1e-6f);
    dpx += dx*inv*pwv; dpy += dy*inv*pwv;
  }
  *(unsigned*)(Hb + (long)t*128 + 2*lane) = (unsigned)f2b(h0a) | ((unsigned)f2b(h1a)<<16);
  if (lane == 0){
    float2 o; o.x = pt.x + dpx; o.y = pt.y + dpy;
    *(float2*)(pf_out + 2*(long)t) = o;
  }
}

// ---------- final layernorm, one wave per node ----------
__global__ __launch_bounds__(256) void ln_kernel(
    const float* __restrict__ xf, const void* __restrict__ g, const void* __restrict__ b,
    void* __restrict__ out, int N, const int* __restrict__ flagp)
{
  const int isbf = *flagp;
  int tid = threadIdx.x, lane = tid & 63;
  int n = blockIdx.x*4 + (tid>>6);
  if (n >= N) return;
  const float* xr = xf + (long)n*128;
  float x0 = xr[2*lane], x1 = xr[2*lane+1];
  float s = x0 + x1, q = x0*x0 + x1*x1;
#pragma unroll
  for (int off=32; off; off>>=1){ s += __shfl_xor(s, off); q += __shfl_xor(q, off); }
  float mu  = s * (1.f/128.f);
  float var = q * (1.f/128.f) - mu*mu;
  float inv = rsqrtf(var + 1e-5f);
  float y0 = (x0-mu)*inv*ldf(g,2*lane,isbf)   + ldf(b,2*lane,isbf);
  float y1 = (x1-mu)*inv*ldf(g,2*lane+1,isbf) + ldf(b,2*lane+1,isbf);
  if (isbf){
    unsigned pk = (unsigned)f2b(y0) | ((unsigned)f2b(y1)<<16);
    *(unsigned*)((u16*)out + (long)n*128 + 2*lane) = pk;
  } else {
    float2 v; v.x = y0; v.y = y1;
    *(float2*)((float*)out + (long)n*128 + 2*lane) = v;
  }
}

extern "C" void kernel_launch(void* const* d_in, const int* in_sizes, int n_in,
                              void* d_out, int out_size, void* d_ws, size_t ws_size,
                              hipStream_t stream)
{
  const void* nf  = d_in[0];
  const void* pos = d_in[1];
  const void* npw = d_in[3];
  const void* npb = d_in[4];
  const void* ew1 = d_in[7];
  const void* eb1 = d_in[8];
  const void* ew2 = d_in[9];
  const void* eb2 = d_in[10];
  const void* nw1 = d_in[11];
  const void* nb1 = d_in[12];
  const void* nw2 = d_in[13];
  const void* nb2 = d_in[14];
  const void* pw1 = d_in[15];
  const void* pb1 = d_in[16];
  const void* pw2 = d_in[17];
  const void* pb2 = d_in[18];
  const void* lng = d_in[19];
  const void* lnb = d_in[20];
  const int* eidx = (const int*)d_in[21];
  const int N = NNODES, E = NEDGES;
  const int* srcp = eidx;
  const int* tgtp = eidx + E;

  char* w = (char*)d_ws;
  size_t off = 0;
  auto alloc = [&](size_t bytes)->char* { char* p = w + off; off += (bytes + 255)/256*256; return p; };
  float* xf    = (float*)alloc((size_t)N*128*4);
  u16*   xb    = (u16*)  alloc((size_t)N*128*2);
  u16*   Ab    = (u16*)  alloc((size_t)N*128*2);
  u16*   Bb    = (u16*)  alloc((size_t)N*128*2);
  u16*   Hb    = (u16*)  alloc((size_t)N*128*2);
  float* pf0   = (float*)alloc((size_t)N*2*4);
  float* pf1   = (float*)alloc((size_t)N*2*4);
  int*   cnt   = (int*)  alloc((size_t)N*4);
  int*   rowptr= (int*)  alloc((size_t)(N+1)*4);
  int*   cursor= (int*)  alloc((size_t)N*4);
  float* degf  = (float*)alloc((size_t)N*4);
  int*   perm  = (int*)  alloc((size_t)E*4);
  int*   bsum  = (int*)  alloc(256*4);
  u16*   pk    = (u16*)  alloc((size_t)28*16384*2);
  float* W12f  = (float*)alloc((size_t)4*16384*4);
  float* ebW   = (float*)alloc(4*128*4);
  float* w2p   = (float*)alloc(4*128*4);
  float* c2p   = (float*)alloc(4*4);
  float* pparm = (float*)alloc(16*4);
  int*   flag  = (int*)  alloc(4);
  u16* hb = Ab;   // Ab dead after agg_kernel

  const int NB = (N + 255)/256;  // 196 <= 256
  detect_kernel<<<1, 64, 0, stream>>>(lng, flag);
  hipMemsetAsync(cnt, 0, (size_t)N*4, stream);
  hist_kernel<<<(E+255)/256, 256, 0, stream>>>(tgtp, cnt, E);
  bsum_kernel<<<NB, 256, 0, stream>>>(cnt, bsum, N);
  bscan_kernel<<<1, 256, 0, stream>>>(bsum, NB);
  csr_kernel<<<NB, 256, 0, stream>>>(cnt, bsum, rowptr, cursor, degf, N);
  scatter_kernel<<<(E+255)/256, 256, 0, stream>>>(srcp, tgtp, cursor, perm, E);
  pack_kernel<<<192, 256, 0, stream>>>(ew1, ew2, nw1, nw2, pk, flag);
  w12_kernel<<<512, 128, 0, stream>>>(ew2, nw1, W12f, flag);
  ebw_kernel<<<4, 128, 0, stream>>>(eb2, nw1, ebW, flag);
  pack2_kernel<<<32, 256, 0, stream>>>(W12f, pk);
  w2p_kernel<<<4, 128, 0, stream>>>(ew2, eb2, pw1, w2p, c2p, flag);
  pparm_kernel<<<1, 64, 0, stream>>>(pw1, pb1, pw2, pb2, pparm, flag);
  proj_kernel<<<(N+1)/2, 256, 0, stream>>>(nf, npw, npb, xf, xb, N, flag);
  cvtp_kernel<<<(2*N+255)/256, 256, 0, stream>>>(pos, pf0, 2*N, flag);

  const int GMM = (N + 63)/64;
  for (int l = 0; l < 4; l++){
    const u16* W1a  = pk + (l*6+0)*16384;
    const u16* W1b  = pk + (l*6+1)*16384;
    const u16* NW1a = pk + (l*6+3)*16384;
    const u16* NW2p = pk + (l*6+5)*16384;
    const u16* W12p = pk + (24+l)*16384;
    float* pin  = (l & 1) ? pf1 : pf0;
    float* pout = (l & 1) ? pf0 : pf1;

    mmab_kernel<<<GMM,256,0,stream>>>(xb, W1a, W1b, eb1, (long)l*128, Ab, Bb, N, flag);
    agg_kernel<<<(N+3)/4, 256, 0, stream>>>(
        rowptr, perm, pin, Ab, Bb,
        ew1, (long)l*257*128 + 256*128,
        w2p + l*128, c2p + l, pparm + l*4,
        Hb, pout, N, flag);
    // hidden = silu(x@NW1a + Hb@(EW2@NW1b) + deg*(eb2@NW1b) + nb1)
    mm128_kernel<1,1,0,1,1><<<GMM,256,0,stream>>>(xb, NW1a, Hb, W12p,
        nb1, (long)l*128, degf, ebW + l*128, nullptr, hb, N, flag);
    // x += hidden@NW2 + nb2
    mm128_kernel<0,0,1,0,1><<<GMM,256,0,stream>>>(hb, NW2p, nullptr, nullptr,
        nb2, (long)l*128, nullptr, nullptr, xf, xb, N, flag);
  }
  ln_kernel<<<(N+3)/4, 256, 0, stream>>>(xf, lng, lnb, d_out, N, flag);
}

// Round 5
// 658.787 us; speedup vs baseline: 2.2844x; 1.1180x over previous
//
#include <hip/hip_runtime.h>
#include <hip/hip_bf16.h>

// EGNN encoder, N=50000, E=250000, D=128, L=4. bf16 inputs/output (verified R2).
// R3: CSR-by-tgt aggregation (no atomics), fused A/B matmul, EW2@NW1b folding.
// R4: 3-stage parallel CSR scan.
// R5: agg_kernel chunked x4 (ILP over serial edge chain), v_rcp_f32 instead of
//     full-precision divides, scalarized CSR loads.

#define NNODES 50000
#define NEDGES 250000

typedef unsigned short u16;
typedef __attribute__((ext_vector_type(8))) short bf16x8;
typedef __attribute__((ext_vector_type(4))) float floatx4;

__device__ __forceinline__ float b2f(u16 h){ unsigned u=((unsigned)h)<<16; float f; __builtin_memcpy(&f,&u,4); return f; }
__device__ __forceinline__ u16 f2b(float f){ unsigned u; __builtin_memcpy(&u,&f,4); u = u + 0x7FFFu + ((u>>16)&1u); return (u16)(u>>16); }
// fast silu: v_exp + v_rcp (1 ulp), fine vs 2%-of-absmax threshold
__device__ __forceinline__ float siluf(float x){ return x*__builtin_amdgcn_rcpf(1.f+__expf(-x)); }
__device__ __forceinline__ float ldf(const void* p, long i, int isbf){
  return isbf ? b2f(((const u16*)p)[i]) : ((const float*)p)[i];
}

__global__ void detect_kernel(const void* lng, int* flag){
  if (threadIdx.x==0 && blockIdx.x==0) *flag = (((const u16*)lng)[0] != 0) ? 1 : 0;
}

// ---------- weight packing into MFMA B-fragment order (24 input matrices) ----------
__global__ __launch_bounds__(256) void pack_kernel(
    const void* __restrict__ ew1, const void* __restrict__ ew2,
    const void* __restrict__ nw1, const void* __restrict__ nw2,
    u16* __restrict__ packed, const int* __restrict__ flagp)
{
  const int isbf = *flagp;
  int t = blockIdx.x*256 + threadIdx.x;       // 24 * 2048
  int m = t >> 11; int r = t & 2047;
  int lane = r & 63; int ntk = r >> 6;
  int kk = ntk >> 3, nt = ntk & 7;
  int l = m/6, w = m%6;
  const void* src; long off;
  switch(w){
    case 0: src=ew1; off=(long)l*257*128;            break; // W1a
    case 1: src=ew1; off=(long)l*257*128 + 128*128;  break; // W1b
    case 2: src=ew2; off=(long)l*128*128;            break; // EW2
    case 3: src=nw1; off=(long)l*256*128;            break; // NW1a
    case 4: src=nw1; off=(long)l*256*128 + 128*128;  break; // NW1b
    default:src=nw2; off=(long)l*128*128;            break; // NW2
  }
  int c  = nt*16 + (lane & 15);
  int k0 = kk*32 + (lane >> 4)*8;
  u16 vals[8];
#pragma unroll
  for (int j=0;j<8;j++){
    long idx = off + (long)(k0+j)*128 + c;
    vals[j] = isbf ? ((const u16*)src)[idx] : f2b(((const float*)src)[idx]);
  }
  bf16x8 v; __builtin_memcpy(&v, vals, 16);
  *(bf16x8*)(packed + (long)t*8) = v;
}

// ---------- pack fp32 W12[l] (4 matrices) into chunks 24..27 ----------
__global__ __launch_bounds__(256) void pack2_kernel(
    const float* __restrict__ W12f, u16* __restrict__ packed)
{
  int t = blockIdx.x*256 + threadIdx.x;       // 4 * 2048
  int m = t >> 11; int r = t & 2047;
  int lane = r & 63; int ntk = r >> 6;
  int kk = ntk >> 3, nt = ntk & 7;
  const float* base = W12f + (long)m*16384;
  int c  = nt*16 + (lane & 15);
  int k0 = kk*32 + (lane >> 4)*8;
  u16 vals[8];
#pragma unroll
  for (int j=0;j<8;j++) vals[j] = f2b(base[(long)(k0+j)*128 + c]);
  bf16x8 v; __builtin_memcpy(&v, vals, 16);
  *(bf16x8*)(packed + ((long)(24+m)*2048 + r)*8) = v;
}

// ---------- W12[l][k][j] = sum_d EW2[l][k][d]*NW1b[l][d][j] (fp32) ----------
__global__ __launch_bounds__(128) void w12_kernel(
    const void* __restrict__ ew2, const void* __restrict__ nw1,
    float* __restrict__ W12f, const int* __restrict__ flagp)
{
  const int isbf = *flagp;
  int l = blockIdx.x >> 7, k = blockIdx.x & 127, j = threadIdx.x;
  long e2 = (long)l*16384 + (long)k*128;
  long nb = (long)l*256*128 + 128*128;
  float acc = 0.f;
  for (int d=0; d<128; d++)
    acc += ldf(ew2, e2 + d, isbf) * ldf(nw1, nb + (long)d*128 + j, isbf);
  W12f[(long)l*16384 + (long)k*128 + j] = acc;
}

// ---------- ebW[l][j] = sum_d eb2[l][d]*NW1b[l][d][j] ----------
__global__ __launch_bounds__(128) void ebw_kernel(
    const void* __restrict__ eb2, const void* __restrict__ nw1,
    float* __restrict__ ebW, const int* __restrict__ flagp)
{
  const int isbf = *flagp;
  int l = blockIdx.x, j = threadIdx.x;
  long nb = (long)l*256*128 + 128*128;
  float acc = 0.f;
  for (int d=0; d<128; d++)
    acc += ldf(eb2, (long)l*128 + d, isbf) * ldf(nw1, nb + (long)d*128 + j, isbf);
  ebW[l*128+j] = acc;
}

// ---------- per-layer w2p = EW2 @ pw1[0:128], c2p = eb2 . pw1[0:128] ----------
__global__ __launch_bounds__(128) void w2p_kernel(
    const void* __restrict__ ew2, const void* __restrict__ eb2, const void* __restrict__ pw1,
    float* __restrict__ w2p, float* __restrict__ c2p, const int* __restrict__ flagp)
{
  const int isbf = *flagp;
  int l = blockIdx.x, i = threadIdx.x;
  long Woff = (long)l*128*128, poff = (long)l*129;
  float acc = 0.f;
  for (int j=0;j<128;j++) acc += ldf(ew2, Woff + (long)i*128 + j, isbf) * ldf(pw1, poff + j, isbf);
  w2p[l*128+i] = acc;
  __shared__ float red[128];
  red[i] = ldf(eb2, (long)l*128 + i, isbf) * ldf(pw1, poff + i, isbf);
  __syncthreads();
  for (int st=64; st>0; st>>=1){ if (i<st) red[i]+=red[i+st]; __syncthreads(); }
  if (i==0) c2p[l] = red[0];
}

__global__ void pparm_kernel(const void* pw1, const void* pb1, const void* pw2, const void* pb2,
                             float* pparm, const int* flagp)
{
  const int isbf = *flagp;
  int l = threadIdx.x;
  if (l < 4){
    pparm[l*4+0] = ldf(pw1, (long)l*129 + 128, isbf);
    pparm[l*4+1] = ldf(pb1, l, isbf);
    pparm[l*4+2] = ldf(pw2, l, isbf);
    pparm[l*4+3] = ldf(pb2, l, isbf);
  }
}

// ---------- CSR build: histogram, 3-stage scan, scatter ----------
__global__ __launch_bounds__(256) void hist_kernel(const int* __restrict__ tgt, int* __restrict__ cnt, int E){
  int i = blockIdx.x*256 + threadIdx.x;
  if (i < E) atomicAdd(&cnt[tgt[i]], 1);
}

__global__ __launch_bounds__(256) void bsum_kernel(const int* __restrict__ cnt, int* __restrict__ bsum, int N){
  int i = blockIdx.x*256 + threadIdx.x;
  int v = (i < N) ? cnt[i] : 0;
#pragma unroll
  for (int off=32; off; off>>=1) v += __shfl_down(v, off);
  __shared__ int ws[4];
  if ((threadIdx.x & 63) == 0) ws[threadIdx.x>>6] = v;
  __syncthreads();
  if (threadIdx.x == 0) bsum[blockIdx.x] = ws[0]+ws[1]+ws[2]+ws[3];
}

__global__ __launch_bounds__(256) void bscan_kernel(int* __restrict__ bsum, int nb){
  __shared__ int lds[256];
  int i = threadIdx.x;
  int v = (i < nb) ? bsum[i] : 0;
  lds[i] = v; __syncthreads();
#pragma unroll
  for (int off=1; off<256; off<<=1){
    int t = (i>=off)? lds[i-off] : 0; __syncthreads();
    lds[i] += t; __syncthreads();
  }
  if (i < nb) bsum[i] = lds[i] - v;  // exclusive prefix
}

__global__ __launch_bounds__(256) void csr_kernel(
    const int* __restrict__ cnt, const int* __restrict__ bsum,
    int* __restrict__ rowptr, int* __restrict__ cursor, float* __restrict__ degf, int N)
{
  __shared__ int lds[256];
  int i = blockIdx.x*256 + threadIdx.x;
  int c = (i < N) ? cnt[i] : 0;
  lds[threadIdx.x] = c; __syncthreads();
#pragma unroll
  for (int off=1; off<256; off<<=1){
    int t = (threadIdx.x>=off)? lds[threadIdx.x-off] : 0; __syncthreads();
    lds[threadIdx.x] += t; __syncthreads();
  }
  int run = bsum[blockIdx.x] + lds[threadIdx.x] - c;  // exclusive
  if (i < N){
    rowptr[i] = run; cursor[i] = run; degf[i] = (float)c;
    if (i == N-1) rowptr[N] = run + c;
  }
}

__global__ __launch_bounds__(256) void scatter_kernel(
    const int* __restrict__ src, const int* __restrict__ tgt,
    int* __restrict__ cursor, int* __restrict__ permsrc, int E)
{
  int e = blockIdx.x*256 + threadIdx.x;
  if (e >= E) return;
  int t = tgt[e];
  int p = atomicAdd(&cursor[t], 1);
  permsrc[p] = src[e];
}

// ---------- initial projection x = nf @ npw + npb (2 nodes/block) ----------
__global__ __launch_bounds__(256) void proj_kernel(
    const void* __restrict__ nf, const void* __restrict__ W, const void* __restrict__ bvec,
    float* __restrict__ xf, u16* __restrict__ xb, int N, const int* __restrict__ flagp)
{
  const int isbf = *flagp;
  int n = blockIdx.x*2 + (threadIdx.x>>7), d = threadIdx.x & 127;
  if (n >= N) return;
  float acc = ldf(bvec, d, isbf);
#pragma unroll
  for (int f=0; f<12; f++) acc += ldf(nf, (long)n*12+f, isbf) * ldf(W, f*128+d, isbf);
  xf[(long)n*128+d] = acc;
  xb[(long)n*128+d] = f2b(acc);
}

__global__ __launch_bounds__(256) void cvtp_kernel(const void* __restrict__ pos, float* __restrict__ pf,
                                                   int n, const int* __restrict__ flagp){
  const int isbf = *flagp;
  int i = blockIdx.x*256 + threadIdx.x;
  if (i < n) pf[i] = ldf(pos, i, isbf);
}

// ---------- fused A/B matmul: Ab = bf16(x@W1a+eb1), Bb = bf16(x@W1b) ----------
__global__ __launch_bounds__(256) void mmab_kernel(
    const u16* __restrict__ X, const u16* __restrict__ Wa, const u16* __restrict__ Wb,
    const void* __restrict__ bias, long bias_off,
    u16* __restrict__ Ab, u16* __restrict__ Bb, int nrows, const int* __restrict__ flagp)
{
  const int tid = threadIdx.x;
  const int wave = tid>>6, lane = tid&63;
  const int row0 = (blockIdx.x*4 + wave)*16;
  if (row0 >= nrows) return;
  const int isbf = *flagp;
  const int lr = lane&15, lg = lane>>4;
  floatx4 accA[8], accB[8];
#pragma unroll
  for (int i=0;i<8;i++){ accA[i]=(floatx4){0,0,0,0}; accB[i]=(floatx4){0,0,0,0}; }
  int arow = row0 + lr; if (arow >= nrows) arow = nrows-1;
  const u16* xr = X + (long)arow*128;
#pragma unroll
  for (int kk=0;kk<4;kk++){
    bf16x8 a = *(const bf16x8*)(xr + kk*32 + lg*8);
#pragma unroll
    for (int nt=0;nt<8;nt++){
      bf16x8 ba = *(const bf16x8*)(Wa + ((kk*8+nt)*64 + lane)*8);
      accA[nt] = __builtin_amdgcn_mfma_f32_16x16x32_bf16(a, ba, accA[nt], 0, 0, 0);
      bf16x8 bb = *(const bf16x8*)(Wb + ((kk*8+nt)*64 + lane)*8);
      accB[nt] = __builtin_amdgcn_mfma_f32_16x16x32_bf16(a, bb, accB[nt], 0, 0, 0);
    }
  }
#pragma unroll
  for (int r=0;r<4;r++){
    int row = row0 + lg*4 + r;
    if (row >= nrows) continue;
#pragma unroll
    for (int nt=0;nt<8;nt++){
      int col = nt*16 + lr;
      Ab[(long)row*128+col] = f2b(accA[nt][r] + ldf(bias, bias_off + col, isbf));
      Bb[(long)row*128+col] = f2b(accB[nt][r]);
    }
  }
}

// ---------- generic [N,128]@[128,128] bf16 MFMA matmul ----------
template<int DUAL, int SILU, int RES, int FDEG, int BIAS>
__global__ __launch_bounds__(256) void mm128_kernel(
    const u16* __restrict__ X1, const u16* __restrict__ W1p,
    const u16* __restrict__ X2, const u16* __restrict__ W2p,
    const void* __restrict__ bias, long bias_off,
    const float* __restrict__ degf, const float* __restrict__ fdegb,
    float* __restrict__ resF, u16* __restrict__ outB, int nrows,
    const int* __restrict__ flagp)
{
  const int tid = threadIdx.x;
  const int wave = tid>>6, lane = tid&63;
  const int row0 = (blockIdx.x*4 + wave)*16;
  if (row0 >= nrows) return;
  const int isbf = BIAS ? *flagp : 0;
  const int lr = lane&15, lg = lane>>4;
  floatx4 acc[8];
#pragma unroll
  for (int i=0;i<8;i++) acc[i] = (floatx4){0.f,0.f,0.f,0.f};
  int arow = row0 + lr; if (arow >= nrows) arow = nrows-1;
  {
    const u16* xr = X1 + (long)arow*128;
#pragma unroll
    for (int kk=0;kk<4;kk++){
      bf16x8 a = *(const bf16x8*)(xr + kk*32 + lg*8);
#pragma unroll
      for (int nt=0;nt<8;nt++){
        bf16x8 b = *(const bf16x8*)(W1p + ((kk*8+nt)*64 + lane)*8);
        acc[nt] = __builtin_amdgcn_mfma_f32_16x16x32_bf16(a, b, acc[nt], 0, 0, 0);
      }
    }
  }
  if (DUAL){
    const u16* xr = X2 + (long)arow*128;
#pragma unroll
    for (int kk=0;kk<4;kk++){
      bf16x8 a = *(const bf16x8*)(xr + kk*32 + lg*8);
#pragma unroll
      for (int nt=0;nt<8;nt++){
        bf16x8 b = *(const bf16x8*)(W2p + ((kk*8+nt)*64 + lane)*8);
        acc[nt] = __builtin_amdgcn_mfma_f32_16x16x32_bf16(a, b, acc[nt], 0, 0, 0);
      }
    }
  }
  // C/D layout: col = lane&15, row = (lane>>4)*4 + reg
#pragma unroll
  for (int r=0;r<4;r++){
    int row = row0 + lg*4 + r;
    if (row >= nrows) continue;
#pragma unroll
    for (int nt=0;nt<8;nt++){
      int col = nt*16 + lr;
      float v = acc[nt][r];
      if (BIAS) v += ldf(bias, bias_off + col, isbf);
      if (FDEG) v += degf[row] * fdegb[col];
      if (SILU) v = siluf(v);
      if (RES){ float t = resF[(long)row*128+col] + v; resF[(long)row*128+col] = t; v = t; }
      outB[(long)row*128+col] = f2b(v);
    }
  }
}

// ---------- CSR aggregation: one wave per target node, chunked x4 ----------
__global__ __launch_bounds__(256) void agg_kernel(
    const int* __restrict__ rowptr, const int* __restrict__ permsrc,
    const float* __restrict__ pf_in,
    const u16* __restrict__ A, const u16* __restrict__ B,
    const void* __restrict__ ew1, long w1c_off,
    const float* __restrict__ w2p, const float* __restrict__ c2pl,
    const float* __restrict__ pp,
    u16* __restrict__ Hb, float* __restrict__ pf_out, int N,
    const int* __restrict__ flagp)
{
  const int isbf = *flagp;
  int tid = threadIdx.x, lane = tid & 63;
  int t = blockIdx.x*4 + (tid>>6);
  if (t >= N) return;
  int tu = __builtin_amdgcn_readfirstlane(t);   // wave-uniform -> scalar loads
  float c0 = ldf(ew1, w1c_off + 2*lane,     isbf);
  float c1 = ldf(ew1, w1c_off + 2*lane + 1, isbf);
  float2 wp = *(const float2*)(w2p + 2*lane);
  float c2 = c2pl[0];
  float p0 = pp[0], p1 = pp[1], p2 = pp[2], p3 = pp[3];
  int jb = rowptr[tu], je = rowptr[tu+1];
  float2 pt = *(const float2*)(pf_in + 2*(long)tu);
  unsigned bv = *(const unsigned*)(B + (long)tu*128 + 2*lane);
  float b0 = b2f((u16)bv), b1 = b2f((u16)(bv>>16));
  float h0a = 0.f, h1a = 0.f, dpx = 0.f, dpy = 0.f;
  for (int j0 = jb; j0 < je; j0 += 4){
    int m = je - j0; if (m > 4) m = 4;
    int s[4]; float2 ps[4]; unsigned av[4];
    float part[4], dist[4], dxv[4], dyv[4];
    // batched index loads (scalar: j0+c uniform)
#pragma unroll
    for (int c=0;c<4;c++) if (c<m) s[c] = permsrc[j0+c];
    // batched data loads — 8 independent loads in flight
#pragma unroll
    for (int c=0;c<4;c++) if (c<m){
      ps[c] = *(const float2*)(pf_in + 2*(long)s[c]);
      av[c] = *(const unsigned*)(A + (long)s[c]*128 + 2*lane);
    }
    // per-edge h / partial dot (ILP across chunk)
#pragma unroll
    for (int c=0;c<4;c++){
      if (c<m){
        float dx = pt.x - ps[c].x, dy = pt.y - ps[c].y;
        float d2 = dx*dx + dy*dy;
        float dd = __builtin_amdgcn_sqrtf(d2);
        float h0 = siluf(b2f((u16)av[c])       + b0 + dd*c0);
        float h1 = siluf(b2f((u16)(av[c]>>16)) + b1 + dd*c1);
        h0a += h0; h1a += h1;
        part[c] = h0*wp.x + h1*wp.y;
        dist[c] = dd; dxv[c] = dx; dyv[c] = dy;
      } else part[c] = 0.f;
    }
    // interleaved butterflies: 4 independent 6-step chains overlap
#pragma unroll
    for (int off=32; off; off>>=1){
#pragma unroll
      for (int c=0;c<4;c++) part[c] += __shfl_xor(part[c], off);
    }
    // per-edge scalar MLP + pos accumulation (ILP across chunk)
#pragma unroll
    for (int c=0;c<4;c++){
      if (c<m){
        float spre = part[c] + c2 + dist[c]*p0 + p1;
        float pwv  = siluf(spre)*p2 + p3;
        float inv  = __builtin_amdgcn_rcpf(dist[c] + 1e-6f);
        dpx += dxv[c]*inv*pwv; dpy += dyv[c]*inv*pwv;
      }
    }
  }
  *(unsigned*)(Hb + (long)tu*128 + 2*lane) = (unsigned)f2b(h0a) | ((unsigned)f2b(h1a)<<16);
  if (lane == 0){
    float2 o; o.x = pt.x + dpx; o.y = pt.y + dpy;
    *(float2*)(pf_out + 2*(long)tu) = o;
  }
}

// ---------- final layernorm, one wave per node ----------
__global__ __launch_bounds__(256) void ln_kernel(
    const float* __restrict__ xf, const void* __restrict__ g, const void* __restrict__ b,
    void* __restrict__ out, int N, const int* __restrict__ flagp)
{
  const int isbf = *flagp;
  int tid = threadIdx.x, lane = tid & 63;
  int n = blockIdx.x*4 + (tid>>6);
  if (n >= N) return;
  const float* xr = xf + (long)n*128;
  float x0 = xr[2*lane], x1 = xr[2*lane+1];
  float s = x0 + x1, q = x0*x0 + x1*x1;
#pragma unroll
  for (int off=32; off; off>>=1){ s += __shfl_xor(s, off); q += __shfl_xor(q, off); }
  float mu  = s * (1.f/128.f);
  float var = q * (1.f/128.f) - mu*mu;
  float inv = rsqrtf(var + 1e-5f);
  float y0 = (x0-mu)*inv*ldf(g,2*lane,isbf)   + ldf(b,2*lane,isbf);
  float y1 = (x1-mu)*inv*ldf(g,2*lane+1,isbf) + ldf(b,2*lane+1,isbf);
  if (isbf){
    unsigned pk = (unsigned)f2b(y0) | ((unsigned)f2b(y1)<<16);
    *(unsigned*)((u16*)out + (long)n*128 + 2*lane) = pk;
  } else {
    float2 v; v.x = y0; v.y = y1;
    *(float2*)((float*)out + (long)n*128 + 2*lane) = v;
  }
}

extern "C" void kernel_launch(void* const* d_in, const int* in_sizes, int n_in,
                              void* d_out, int out_size, void* d_ws, size_t ws_size,
                              hipStream_t stream)
{
  const void* nf  = d_in[0];
  const void* pos = d_in[1];
  const void* npw = d_in[3];
  const void* npb = d_in[4];
  const void* ew1 = d_in[7];
  const void* eb1 = d_in[8];
  const void* ew2 = d_in[9];
  const void* eb2 = d_in[10];
  const void* nw1 = d_in[11];
  const void* nb1 = d_in[12];
  const void* nw2 = d_in[13];
  const void* nb2 = d_in[14];
  const void* pw1 = d_in[15];
  const void* pb1 = d_in[16];
  const void* pw2 = d_in[17];
  const void* pb2 = d_in[18];
  const void* lng = d_in[19];
  const void* lnb = d_in[20];
  const int* eidx = (const int*)d_in[21];
  const int N = NNODES, E = NEDGES;
  const int* srcp = eidx;
  const int* tgtp = eidx + E;

  char* w = (char*)d_ws;
  size_t off = 0;
  auto alloc = [&](size_t bytes)->char* { char* p = w + off; off += (bytes + 255)/256*256; return p; };
  float* xf    = (float*)alloc((size_t)N*128*4);
  u16*   xb    = (u16*)  alloc((size_t)N*128*2);
  u16*   Ab    = (u16*)  alloc((size_t)N*128*2);
  u16*   Bb    = (u16*)  alloc((size_t)N*128*2);
  u16*   Hb    = (u16*)  alloc((size_t)N*128*2);
  float* pf0   = (float*)alloc((size_t)N*2*4);
  float* pf1   = (float*)alloc((size_t)N*2*4);
  int*   cnt   = (int*)  alloc((size_t)N*4);
  int*   rowptr= (int*)  alloc((size_t)(N+1)*4);
  int*   cursor= (int*)  alloc((size_t)N*4);
  float* degf  = (float*)alloc((size_t)N*4);
  int*   perm  = (int*)  alloc((size_t)E*4);
  int*   bsum  = (int*)  alloc(256*4);
  u16*   pk    = (u16*)  alloc((size_t)28*16384*2);
  float* W12f  = (float*)alloc((size_t)4*16384*4);
  float* ebW   = (float*)alloc(4*128*4);
  float* w2p   = (float*)alloc(4*128*4);
  float* c2p   = (float*)alloc(4*4);
  float* pparm = (float*)alloc(16*4);
  int*   flag  = (int*)  alloc(4);
  u16* hb = Ab;   // Ab dead after agg_kernel

  const int NB = (N + 255)/256;  // 196 <= 256
  detect_kernel<<<1, 64, 0, stream>>>(lng, flag);
  hipMemsetAsync(cnt, 0, (size_t)N*4, stream);
  hist_kernel<<<(E+255)/256, 256, 0, stream>>>(tgtp, cnt, E);
  bsum_kernel<<<NB, 256, 0, stream>>>(cnt, bsum, N);
  bscan_kernel<<<1, 256, 0, stream>>>(bsum, NB);
  csr_kernel<<<NB, 256, 0, stream>>>(cnt, bsum, rowptr, cursor, degf, N);
  scatter_kernel<<<(E+255)/256, 256, 0, stream>>>(srcp, tgtp, cursor, perm, E);
  pack_kernel<<<192, 256, 0, stream>>>(ew1, ew2, nw1, nw2, pk, flag);
  w12_kernel<<<512, 128, 0, stream>>>(ew2, nw1, W12f, flag);
  ebw_kernel<<<4, 128, 0, stream>>>(eb2, nw1, ebW, flag);
  pack2_kernel<<<32, 256, 0, stream>>>(W12f, pk);
  w2p_kernel<<<4, 128, 0, stream>>>(ew2, eb2, pw1, w2p, c2p, flag);
  pparm_kernel<<<1, 64, 0, stream>>>(pw1, pb1, pw2, pb2, pparm, flag);
  proj_kernel<<<(N+1)/2, 256, 0, stream>>>(nf, npw, npb, xf, xb, N, flag);
  cvtp_kernel<<<(2*N+255)/256, 256, 0, stream>>>(pos, pf0, 2*N, flag);

  const int GMM = (N + 63)/64;
  for (int l = 0; l < 4; l++){
    const u16* W1a  = pk + (l*6+0)*16384;
    const u16* W1b  = pk + (l*6+1)*16384;
    const u16* NW1a = pk + (l*6+3)*16384;
    const u16* NW2p = pk + (l*6+5)*16384;
    const u16* W12p = pk + (24+l)*16384;
    float* pin  = (l & 1) ? pf1 : pf0;
    float* pout = (l & 1) ? pf0 : pf1;

    mmab_kernel<<<GMM,256,0,stream>>>(xb, W1a, W1b, eb1, (long)l*128, Ab, Bb, N, flag);
    agg_kernel<<<(N+3)/4, 256, 0, stream>>>(
        rowptr, perm, pin, Ab, Bb,
        ew1, (long)l*257*128 + 256*128,
        w2p + l*128, c2p + l, pparm + l*4,
        Hb, pout, N, flag);
    // hidden = silu(x@NW1a + Hb@(EW2@NW1b) + deg*(eb2@NW1b) + nb1)
    mm128_kernel<1,1,0,1,1><<<GMM,256,0,stream>>>(xb, NW1a, Hb, W12p,
        nb1, (long)l*128, degf, ebW + l*128, nullptr, hb, N, flag);
    // x += hidden@NW2 + nb2
    mm128_kernel<0,0,1,0,1><<<GMM,256,0,stream>>>(hb, NW2p, nullptr, nullptr,
        nb2, (long)l*128, nullptr, nullptr, xf, xb, N, flag);
  }
  ln_kernel<<<(N+3)/4, 256, 0, stream>>>(xf, lng, lnb, d_out, N, flag);
}